// Round 12
// baseline (137.763 us; speedup 1.0000x reference)
//
#include <hip/hip_runtime.h>

#define NFREQ   257
#define NFRAMES 3751
#define NS      480000
#define HOP     128
#define WIN     512

#define NB      32
#define BN      64                  // frames per block
#define NFT     60                  // 60*64 = 3840 frames
#define NH      16                  // half-steps: 8 ks * 2 ko (one fpair per block)
#define XWPITCH 272                 // 128 samples (256B) + 16B pad
#define XWROWS  67                  // (64-1)*128+512 = 8576 samples
#define XW_B    18224               // 67 * 272
#define WNYQ_B  1024
#define XGROUPS 1072                // 8576/8

typedef __attribute__((ext_vector_type(8))) short short8;
typedef __attribute__((ext_vector_type(4))) float f32x4;

__device__ __forceinline__ short f2bf(float f) {
    __bf16 b = (__bf16)f;
    return __builtin_bit_cast(short, b);
}
__device__ __forceinline__ float bf2f(short s) {
    unsigned int u = ((unsigned int)(unsigned short)s) << 16;
    return __builtin_bit_cast(float, u);
}
__device__ __forceinline__ void gload_lds16(const void* g, void* l) {
    __builtin_amdgcn_global_load_lds(
        (const __attribute__((address_space(1))) void*)g,
        (__attribute__((address_space(3))) void*)l, 16, 0, 0);
}

// ---- prep: abf[2][256][512] bf16 (linear cast) + nyq row (real row 256) ----
__global__ __launch_bounds__(256)
void prep_basis3(const float* __restrict__ basis,
                 short* __restrict__ abf, short* __restrict__ wnyqG) {
    int g = blockIdx.x * 256 + threadIdx.x;
    if (g < 32768) {
        int plane = g >> 14;
        int rem   = g & 16383;
        int row   = rem >> 6;
        int kg    = rem & 63;
        const float4* p = reinterpret_cast<const float4*>(
            basis + ((size_t)(plane * NFREQ + row)) * WIN + kg * 8);
        float4 a0 = p[0], a1 = p[1];
        short8 v;
        v[0]=f2bf(a0.x); v[1]=f2bf(a0.y); v[2]=f2bf(a0.z); v[3]=f2bf(a0.w);
        v[4]=f2bf(a1.x); v[5]=f2bf(a1.y); v[6]=f2bf(a1.z); v[7]=f2bf(a1.w);
        *reinterpret_cast<short8*>(abf + ((size_t)(plane * 256 + row)) * WIN + kg * 8) = v;
    } else if (g < 32832) {
        int j = g - 32768;
        const float4* p = reinterpret_cast<const float4*>(basis + (size_t)256 * WIN + j * 8);
        float4 a0 = p[0], a1 = p[1];
        short8 v;
        v[0]=f2bf(a0.x); v[1]=f2bf(a0.y); v[2]=f2bf(a0.z); v[3]=f2bf(a0.w);
        v[4]=f2bf(a1.x); v[5]=f2bf(a1.y); v[6]=f2bf(a1.z); v[7]=f2bf(a1.w);
        *reinterpret_cast<short8*>(wnyqG + j * 8) = v;
    }
}

// ---- main: fp plane x 64 frames per block; barrier-free; A global->VGPR ----
__global__ __launch_bounds__(256, 3)
void stft_mfma_kernel(const float* __restrict__ x,
                      const short* __restrict__ abf,
                      const short* __restrict__ wnyqG,
                      float* __restrict__ out)
{
    __shared__ __align__(16) char smem[XW_B + WNYQ_B];   // 19248 B
    char* const xw   = smem;
    char* const wnyq = smem + XW_B;

    const int tid  = threadIdx.x;
    const int wave = tid >> 6;          // 0..3 : freq sub-row (32 rows each)
    const int lane = tid & 63;
    const int lgrp = lane >> 4;
    const int l15  = lane & 15;

    // bijective XCD chunk swizzle: 3840 = 8 * 480; fp is the fastest bit so the
    // fp0/fp1 pair sharing one X window is adjacent on the same XCD (L2 hit)
    const int logical = (blockIdx.x & 7) * 480 + (blockIdx.x >> 3);
    const int fp   = logical & 1;
    const int rest = logical >> 1;
    const int ft = rest % NFT;
    const int b  = rest / NFT;
    const int t0 = ft * BN;

    if (wave == 0 && fp == 0)
        gload_lds16((const char*)wnyqG + lane * 16, wnyq);

    // ---- prologue: fp32 x window -> bf16 LDS, padded rows, reflect at edges ----
    {
        const float* __restrict__ xb = x + (size_t)b * NS;
        const int sbase = t0 * 128 - 256;
        #pragma unroll
        for (int i = 0; i < 5; ++i) {
            int g = tid + i * 256;                 // 8-sample (16B) group
            if (g < XGROUPS) {
                int ix = sbase + g * 8;
                short8 v;
                if (ix >= 0 && ix + 8 <= NS) {
                    const float4* p = reinterpret_cast<const float4*>(xb + ix);
                    float4 a0 = p[0], a1 = p[1];
                    v[0]=f2bf(a0.x); v[1]=f2bf(a0.y); v[2]=f2bf(a0.z); v[3]=f2bf(a0.w);
                    v[4]=f2bf(a1.x); v[5]=f2bf(a1.y); v[6]=f2bf(a1.z); v[7]=f2bf(a1.w);
                } else {
                    #pragma unroll
                    for (int q = 0; q < 8; ++q) {
                        int idx = ix + q;
                        if (idx < 0) idx = -idx;
                        if (idx >= NS + 256) { v[q] = 0; continue; }
                        if (idx >= NS) idx = 2 * NS - 2 - idx;
                        v[q] = f2bf(xb[idx]);
                    }
                }
                *reinterpret_cast<short8*>(xw + (g >> 4) * XWPITCH + (g & 15) * 16) = v;
            }
        }
    }
    __syncthreads();    // the ONLY barrier

    // per-lane A base: fpair offset + row = wave*32 + l15 (+m*16), k-elem = lgrp*8
    const char* const aB = (const char*)abf + fp * 131072
                         + wave * 32768 + l15 * 1024 + lgrp * 16;

    f32x4 accR[2][4], accI[2][4];
    #pragma unroll
    for (int m = 0; m < 2; ++m)
        #pragma unroll
        for (int n = 0; n < 4; ++n) {
            accR[m][n] = f32x4{0.f,0.f,0.f,0.f};
            accI[m][n] = f32x4{0.f,0.f,0.f,0.f};
        }

    short8 R0[2], I0[2], R1[2], I1[2];

    // h -> byte offset: ks=(h>>1)&7 (<<7), ko=h&1 (<<6)
    #define AOFF(h) (((((h) >> 1) & 7) << 7) + (((h) & 1) << 6))

    // prologue loads: half-step 0 into set0
    #pragma unroll
    for (int m = 0; m < 2; ++m) {
        R0[m] = *reinterpret_cast<const short8*>(aB + m * 16384);
        I0[m] = *reinterpret_cast<const short8*>(aB + 262144 + m * 16384);
    }

    #define COMPUTE(h, R, I)                                                        \
    {                                                                               \
        int r8 = ((((h) >> 1) & 7) << 7) + (((h) & 1) << 6) + lgrp * 16;            \
        int T  = r8 + ((r8 >> 4) & 0x30);                                           \
        const char* xwl = xw + l15 * XWPITCH + T;                                   \
        short8 xv[4];                                                               \
        _Pragma("unroll")                                                           \
        for (int j = 0; j < 4; ++j)                                                 \
            xv[j] = *reinterpret_cast<const short8*>(xwl + j * (16 * XWPITCH));     \
        _Pragma("unroll")                                                           \
        for (int m = 0; m < 2; ++m)                                                 \
            _Pragma("unroll")                                                       \
            for (int j = 0; j < 4; ++j) {                                           \
                accR[m][j] = __builtin_amdgcn_mfma_f32_16x16x32_bf16(               \
                    (R)[m], xv[j], accR[m][j], 0, 0, 0);                            \
                accI[m][j] = __builtin_amdgcn_mfma_f32_16x16x32_bf16(               \
                    (I)[m], xv[j], accI[m][j], 0, 0, 0);                            \
            }                                                                       \
    }

    #pragma unroll 1
    for (int hh = 0; hh < NH; hh += 2) {
        {   // prefetch h = hh+1 into set1
            const int boff = AOFF(hh + 1);
            #pragma unroll
            for (int m = 0; m < 2; ++m) {
                R1[m] = *reinterpret_cast<const short8*>(aB + boff + m * 16384);
                I1[m] = *reinterpret_cast<const short8*>(aB + boff + 262144 + m * 16384);
            }
        }
        COMPUTE(hh, R0, I0);
        if (hh + 2 < NH) {   // prefetch h = hh+2 into set0
            const int boff = AOFF(hh + 2);
            #pragma unroll
            for (int m = 0; m < 2; ++m) {
                R0[m] = *reinterpret_cast<const short8*>(aB + boff + m * 16384);
                I0[m] = *reinterpret_cast<const short8*>(aB + boff + 262144 + m * 16384);
            }
        }
        COMPUTE(hh + 1, R1, I1);
    }

    // ---- epilogue: magnitude + store (f = fp*128 + 0..127, all < 257) ----
    {
        float* ob = out + (size_t)b * NFREQ * NFRAMES;
        const int fb = fp * 128 + wave * 32 + lgrp * 4;
        const int tb = t0 + l15;
        #pragma unroll
        for (int m = 0; m < 2; ++m)
            #pragma unroll
            for (int nt = 0; nt < 4; ++nt) {
                int t = tb + nt * 16;
                if (t < NFRAMES) {
                    #pragma unroll
                    for (int r = 0; r < 4; ++r) {
                        int f = fb + m * 16 + r;
                        float vr = accR[m][nt][r], vi = accI[m][nt][r];
                        ob[(size_t)f * NFRAMES + t] = sqrtf(vr * vr + vi * vi);
                    }
                }
            }
    }

    // ---- Nyquist tail (fp==0 blocks only): f=256, |dot(x_frame, w)| ----
    // 4 lanes per frame: lane quarter lgrp covers window quarter (one full row)
    if (fp == 0) {
        const int fl = wave * 16 + l15;               // local frame 0..63
        const int xbase = (fl + lgrp) * XWPITCH;      // row fl+lgrp = quarter lgrp
        const int wbase = lgrp * 256;                 // 128 samples = 256 B
        float acc = 0.f;
        #pragma unroll
        for (int j = 0; j < 16; ++j) {
            short8 xv8 = *reinterpret_cast<const short8*>(xw + xbase + j * 16);
            short8 wv8 = *reinterpret_cast<const short8*>(wnyq + wbase + j * 16);
            #pragma unroll
            for (int q = 0; q < 8; ++q)
                acc = fmaf(bf2f(xv8[q]), bf2f(wv8[q]), acc);
        }
        acc += __shfl_xor(acc, 16);
        acc += __shfl_xor(acc, 32);
        int t = t0 + fl;
        if (lgrp == 0 && t < NFRAMES)
            out[((size_t)b * NFREQ + 256) * NFRAMES + t] = fabsf(acc);
    }
}

extern "C" void kernel_launch(void* const* d_in, const int* in_sizes, int n_in,
                              void* d_out, int out_size, void* d_ws, size_t ws_size,
                              hipStream_t stream) {
    const float* x     = (const float*)d_in[0];
    const float* basis = (const float*)d_in[1];
    float* out = (float*)d_out;

    short* abf   = (short*)d_ws;                      // 2*256*512 bf16 = 512 KB
    short* wnyqG = abf + 262144;                      // 512 bf16

    prep_basis3<<<dim3(129), 256, 0, stream>>>(basis, abf, wnyqG);
    stft_mfma_kernel<<<dim3(2 * NFT * NB), 256, 0, stream>>>(x, abf, wnyqG, out);  // 3840 blocks
}

// Round 13
// 87.649 us; speedup vs baseline: 1.5717x; 1.5717x over previous
//
#include <hip/hip_runtime.h>

#define NFREQ   257
#define NFRAMES 3751
#define NS      480000
#define HOP     128
#define WIN     512

#define NB      32
#define BN      128                 // frames per block
#define NFT     30                  // 30*128 = 3840 frames
#define STEPS   32                  // 2 fp * 16 k32
#define XWPITCH 272                 // 128 samples (256B) + 16B pad
#define XW_B    35632               // 131 rows * 272
#define AHALF   16384               // one A step image: [2pl][64r][128B]
#define WNYQ_B  1024
#define XGROUPS 2096

typedef __attribute__((ext_vector_type(8))) short short8;
typedef __attribute__((ext_vector_type(4))) float f32x4;

__device__ __forceinline__ short f2bf(float f) {
    __bf16 b = (__bf16)f;
    return __builtin_bit_cast(short, b);
}
__device__ __forceinline__ float bf2f(short s) {
    unsigned int u = ((unsigned int)(unsigned short)s) << 16;
    return __builtin_bit_cast(float, u);
}
__device__ __forceinline__ void gload_lds16(const void* g, void* l) {
    __builtin_amdgcn_global_load_lds(
        (const __attribute__((address_space(1))) void*)g,
        (__attribute__((address_space(3))) void*)l, 16, 0, 0);
}

// ---- prep: bake 32-step A stream. Image byte ob (16B group g=ob/16):
// step=ob>>14, pl=(ob>>13)&1, r=(ob>>7)&63, s=(ob>>4)&7 ->
// u=s^(r&7), f=r+(u>>2)*64, kg=u&3; holds basis[pl, fp*128+f, ks32*32+kg*8 ..+8]
__global__ __launch_bounds__(256)
void prep_basis4(const float* __restrict__ basis,
                 short* __restrict__ abL, short* __restrict__ wnyqG) {
    int g = blockIdx.x * 256 + threadIdx.x;
    if (g < 32768) {
        int ob   = g * 16;
        int step = ob >> 14;                 // 0..31
        int rem  = ob & 16383;
        int pl   = rem >> 13;
        int r    = (rem >> 7) & 63;
        int s    = (rem >> 4) & 7;
        int u    = s ^ (r & 7);
        int f    = r + (u >> 2) * 64;        // 0..127
        int kg   = u & 3;
        int fp   = step >> 4;
        int ks32 = step & 15;
        int row  = pl * NFREQ + fp * 128 + f;   // < 2*257
        int k0   = ks32 * 32 + kg * 8;
        const float4* p = reinterpret_cast<const float4*>(
            basis + (size_t)row * WIN + k0);
        float4 a0 = p[0], a1 = p[1];
        short8 v;
        v[0]=f2bf(a0.x); v[1]=f2bf(a0.y); v[2]=f2bf(a0.z); v[3]=f2bf(a0.w);
        v[4]=f2bf(a1.x); v[5]=f2bf(a1.y); v[6]=f2bf(a1.z); v[7]=f2bf(a1.w);
        *reinterpret_cast<short8*>(reinterpret_cast<char*>(abL) + ob) = v;
    } else if (g < 32832) {                  // nyq row: real plane row 256
        int j = g - 32768;
        const float4* p = reinterpret_cast<const float4*>(basis + (size_t)256 * WIN + j * 8);
        float4 a0 = p[0], a1 = p[1];
        short8 v;
        v[0]=f2bf(a0.x); v[1]=f2bf(a0.y); v[2]=f2bf(a0.z); v[3]=f2bf(a0.w);
        v[4]=f2bf(a1.x); v[5]=f2bf(a1.y); v[6]=f2bf(a1.z); v[7]=f2bf(a1.w);
        *reinterpret_cast<short8*>(wnyqG + j * 8) = v;
    }
}

// ---- main: 4 waves stacked in freq (128f x 128t tile), wave 32f x 128t ----
__global__ __launch_bounds__(256, 2)
void stft_mfma_kernel(const float* __restrict__ x,
                      const short* __restrict__ abL,
                      const short* __restrict__ wnyqG,
                      float* __restrict__ out)
{
    __shared__ __align__(16) char smem[XW_B + 2 * AHALF + WNYQ_B];  // 69424 B
    char* const xw   = smem;
    char* const aBuf = smem + XW_B;
    char* const wnyq = smem + XW_B + 2 * AHALF;

    const int tid  = threadIdx.x;
    const int wave = tid >> 6;          // 0..3 : freq stack (32 rows each)
    const int lane = tid & 63;
    const int lgrp = lane >> 4;
    const int l15  = lane & 15;

    // bijective XCD chunk swizzle: 960 = 8 * 120
    const int logical = (blockIdx.x & 7) * 120 + (blockIdx.x >> 3);
    const int ft = logical % NFT;
    const int b  = logical / NFT;
    const int t0 = ft * BN;

    const char* abLc = (const char*)abL;

    // ---- prologue: issue step-0 A stage + nyq weights ----
    #pragma unroll
    for (int i = 0; i < 4; ++i) {
        int c = wave * 4 + i;                     // 0..15 KB-chunks
        gload_lds16(abLc + c * 1024 + lane * 16, aBuf + c * 1024);
    }
    if (wave == 0)
        gload_lds16((const char*)wnyqG + lane * 16, wnyq);

    // ---- prologue: fp32 x window -> bf16 LDS, padded rows, reflect edges ----
    {
        const float* __restrict__ xb = x + (size_t)b * NS;
        const int sbase = t0 * 128 - 256;
        #pragma unroll
        for (int i = 0; i < 9; ++i) {
            int g = tid + i * 256;
            if (g < XGROUPS) {
                int ix = sbase + g * 8;
                short8 v;
                if (ix >= 0 && ix + 8 <= NS) {
                    const float4* p = reinterpret_cast<const float4*>(xb + ix);
                    float4 a0 = p[0], a1 = p[1];
                    v[0]=f2bf(a0.x); v[1]=f2bf(a0.y); v[2]=f2bf(a0.z); v[3]=f2bf(a0.w);
                    v[4]=f2bf(a1.x); v[5]=f2bf(a1.y); v[6]=f2bf(a1.z); v[7]=f2bf(a1.w);
                } else {
                    #pragma unroll
                    for (int q = 0; q < 8; ++q) {
                        int idx = ix + q;
                        if (idx < 0) idx = -idx;
                        if (idx >= NS + 256) { v[q] = 0; continue; }
                        if (idx >= NS) idx = 2 * NS - 2 - idx;
                        v[q] = f2bf(xb[idx]);
                    }
                }
                *reinterpret_cast<short8*>(xw + (g >> 4) * XWPITCH + (g & 15) * 16) = v;
            }
        }
    }

    f32x4 accR[2][8], accI[2][8];
    #pragma unroll
    for (int m = 0; m < 2; ++m)
        #pragma unroll
        for (int n = 0; n < 8; ++n) {
            accR[m][n] = f32x4{0.f,0.f,0.f,0.f};
            accI[m][n] = f32x4{0.f,0.f,0.f,0.f};
        }

    // A-read addressing (2-way bank-free): r = (wave&1)*32 + m*16 + l15,
    // u = (wave>>1)*4 + lgrp, slot = u ^ (r&7); off = r*128 + slot*16
    const int rb = (wave & 1) * 32 + l15;
    const int ub = (wave >> 1) * 4 + lgrp;

    #pragma unroll 1
    for (int s = 0; s < STEPS; ++s) {
        // stage(s) loads + X writes visible to all after drain + barrier
        asm volatile("s_waitcnt vmcnt(0)" ::: "memory");
        __builtin_amdgcn_sched_barrier(0);
        __syncthreads();
        __builtin_amdgcn_sched_barrier(0);

        char* const aCur = aBuf + (s & 1) * AHALF;

        // ---- issue NEXT A stage into the other buffer (hidden under compute) ----
        if (s + 1 < STEPS) {
            char* const aNxt = aBuf + ((s + 1) & 1) * AHALF;
            const char* sb = abLc + (size_t)(s + 1) * AHALF;
            #pragma unroll
            for (int i = 0; i < 4; ++i) {
                int c = wave * 4 + i;
                gload_lds16(sb + c * 1024 + lane * 16, aNxt + c * 1024);
            }
        }
        __builtin_amdgcn_sched_barrier(0);   // pin: stage issue precedes compute

        // ---- compute this k32 ----
        const int ks32 = s & 15;
        short8 aRv[2], aIv[2], xv[8];
        #pragma unroll
        for (int m = 0; m < 2; ++m) {
            int r   = rb + m * 16;
            int off = r * 128 + ((ub ^ (r & 7)) << 4);
            aRv[m] = *reinterpret_cast<const short8*>(aCur + off);
            aIv[m] = *reinterpret_cast<const short8*>(aCur + 8192 + off);
        }
        {
            int r8 = ks32 * 64 + lgrp * 16;
            int T  = r8 + ((r8 >> 8) << 4);
            const char* xwl = xw + l15 * XWPITCH + T;
            #pragma unroll
            for (int nt = 0; nt < 8; ++nt)
                xv[nt] = *reinterpret_cast<const short8*>(xwl + nt * (16 * XWPITCH));
        }
        #pragma unroll
        for (int m = 0; m < 2; ++m)
            #pragma unroll
            for (int nt = 0; nt < 8; ++nt) {
                accR[m][nt] = __builtin_amdgcn_mfma_f32_16x16x32_bf16(aRv[m], xv[nt], accR[m][nt], 0, 0, 0);
                accI[m][nt] = __builtin_amdgcn_mfma_f32_16x16x32_bf16(aIv[m], xv[nt], accI[m][nt], 0, 0, 0);
            }

        // ---- per-fp epilogue (after 16 k32 steps) ----
        if ((s & 15) == 15) {
            const int fp = s >> 4;
            float* ob = out + (size_t)b * NFREQ * NFRAMES;
            const int fb = fp * 128 + wave * 32 + lgrp * 4;
            const int tb = t0 + l15;
            #pragma unroll
            for (int m = 0; m < 2; ++m)
                #pragma unroll
                for (int nt = 0; nt < 8; ++nt) {
                    int t = tb + nt * 16;
                    if (t < NFRAMES) {
                        #pragma unroll
                        for (int r = 0; r < 4; ++r) {
                            int f = fb + m * 16 + r;
                            float vr = accR[m][nt][r], vi = accI[m][nt][r];
                            ob[(size_t)f * NFRAMES + t] = sqrtf(vr * vr + vi * vi);
                        }
                    }
                    accR[m][nt] = f32x4{0.f,0.f,0.f,0.f};
                    accI[m][nt] = f32x4{0.f,0.f,0.f,0.f};
                }
        }
    }

    // ---- Nyquist tail: f=256, |dot(x_frame, w)|; x & w in LDS ----
    {
        const int fl = wave * 32 + (lane & 31);       // local frame 0..127
        const int h  = lane >> 5;                     // window half
        const int xbase = (fl + 2 * h) * XWPITCH;
        const int wbase = h * 512;
        float acc = 0.f;
        #pragma unroll
        for (int j = 0; j < 32; ++j) {
            short8 xv8 = *reinterpret_cast<const short8*>(
                xw + xbase + (j >> 4) * XWPITCH + (j & 15) * 16);
            short8 wv8 = *reinterpret_cast<const short8*>(wnyq + wbase + j * 16);
            #pragma unroll
            for (int q = 0; q < 8; ++q)
                acc = fmaf(bf2f(xv8[q]), bf2f(wv8[q]), acc);
        }
        acc += __shfl_xor(acc, 32);
        int t = t0 + fl;
        if (h == 0 && t < NFRAMES)
            out[((size_t)b * NFREQ + 256) * NFRAMES + t] = fabsf(acc);
    }
}

extern "C" void kernel_launch(void* const* d_in, const int* in_sizes, int n_in,
                              void* d_out, int out_size, void* d_ws, size_t ws_size,
                              hipStream_t stream) {
    const float* x     = (const float*)d_in[0];
    const float* basis = (const float*)d_in[1];
    float* out = (float*)d_out;

    short* abL   = (short*)d_ws;                      // 32 steps x 16KB = 512KB
    short* wnyqG = abL + 262144;                      // 512 bf16

    prep_basis4<<<dim3(129), 256, 0, stream>>>(basis, abL, wnyqG);
    stft_mfma_kernel<<<dim3(NFT * NB), 256, 0, stream>>>(x, abL, wnyqG, out);  // 960 blocks
}